// Round 2
// baseline (678.484 us; speedup 1.0000x reference)
//
#include <hip/hip_runtime.h>
#include <math.h>

// Problem shape (fixed by setup_inputs): B=32, C=200, H=128, W=128, fp32.
// One block per (b,c) plane; 512 threads x 8 float4 = 4096 float4 = 16384 elems.
//
// v2 theory: the previous register-resident variant (16 float4/thread live
// across the barrier) was latency/occupancy-bound at 1.25 TB/s effective.
// Here phase 1 streams the plane for min/max WITHOUT retaining it (low VGPR,
// high occupancy), and phase 2 re-reads it from L2/L3 (64KB plane, in-flight
// working set ~64MB << 256MB L3). Map output uses non-temporal stores so the
// 419MB write stream does not evict the input lines we re-read.
//
// v2.1: __builtin_nontemporal_store needs a native clang vector type, not
// HIP's float4 class — use ext_vector_type(4) alias for the store.

#define HW_ELEMS 16384   // 128*128
#define WDIM 128
#define NT 512           // threads per block (8 waves)
#define F4PT 8           // float4 per thread: 4096/512

typedef float nfloat4 __attribute__((ext_vector_type(4)));

__global__ __launch_bounds__(NT) void cm2kp_kernel(
    const float* __restrict__ in,
    float* __restrict__ map_out,
    float* __restrict__ kp_out,
    float* __restrict__ zeta_out)
{
    const int bc = blockIdx.x;
    const float4* __restrict__ src = (const float4*)(in + (size_t)bc * HW_ELEMS);
    nfloat4* __restrict__ dst = (nfloat4*)(map_out + (size_t)bc * HW_ELEMS);
    const int t = threadIdx.x;
    const int wave = t >> 6;
    const int lane = t & 63;

    // ---- Phase 1: streaming per-thread min/max (no data retention) ----
    float vmin =  3.402823466e38f;
    float vmax = -3.402823466e38f;
    #pragma unroll
    for (int i = 0; i < F4PT; ++i) {
        const float4 v = src[i * NT + t];               // coalesced, allocates in L2/L3
        vmin = fminf(vmin, fminf(fminf(v.x, v.y), fminf(v.z, v.w)));
        vmax = fmaxf(vmax, fmaxf(fmaxf(v.x, v.y), fmaxf(v.z, v.w)));
    }
    #pragma unroll
    for (int off = 32; off > 0; off >>= 1) {
        vmin = fminf(vmin, __shfl_down(vmin, off, 64));
        vmax = fmaxf(vmax, __shfl_down(vmax, off, 64));
    }
    __shared__ float smin[8], smax[8];
    if (lane == 0) { smin[wave] = vmin; smax[wave] = vmax; }
    __syncthreads();
    float bmin = smin[0], bmax = smax[0];
    #pragma unroll
    for (int w = 1; w < 8; ++w) {
        bmin = fminf(bmin, smin[w]);
        bmax = fmaxf(bmax, smax[w]);
    }
    // Reference divides by max (NOT max-min). One IEEE divide per block,
    // then multiply: <=1 ulp extra error vs per-element divide (verified).
    const float inv = 1.0f / bmax;

    // ---- Phase 2: re-read from cache, normalize, nt-store, accumulate ----
    float zeta = 0.0f, kpx = 0.0f, kpy = 0.0f;
    #pragma unroll
    for (int i = 0; i < F4PT; ++i) {
        const int idx = i * NT + t;
        const float4 v = src[idx];                      // L2/L3 hit (just read it)
        const int e = idx * 4;                          // element offset in plane
        const float x0 = (float)(e & (WDIM - 1));       // w coord (128%4==0, no wrap)
        const float y0 = (float)(e >> 7);               // h coord
        nfloat4 m;
        m.x = (v.x - bmin) * inv;
        m.y = (v.y - bmin) * inv;
        m.z = (v.z - bmin) * inv;
        m.w = (v.w - bmin) * inv;
        __builtin_nontemporal_store(m, &dst[idx]);      // stream out, don't pollute cache
        const float s = m.x + m.y + m.z + m.w;
        zeta += s;
        // m.x*x0 + m.y*(x0+1) + m.z*(x0+2) + m.w*(x0+3) = s*x0 + m.y + 2m.z + 3m.w
        kpx  += s * x0 + m.y + 2.0f * m.z + 3.0f * m.w;
        kpy  += s * y0;
    }

    #pragma unroll
    for (int off = 32; off > 0; off >>= 1) {
        zeta += __shfl_down(zeta, off, 64);
        kpx  += __shfl_down(kpx,  off, 64);
        kpy  += __shfl_down(kpy,  off, 64);
    }
    __shared__ float sz[8], sx[8], sy[8];
    if (lane == 0) { sz[wave] = zeta; sx[wave] = kpx; sy[wave] = kpy; }
    __syncthreads();
    if (t == 0) {
        float Z = 0.0f, X = 0.0f, Y = 0.0f;
        #pragma unroll
        for (int w = 0; w < 8; ++w) { Z += sz[w]; X += sx[w]; Y += sy[w]; }
        zeta_out[bc] = Z;
        // jnp.round = half-to-even -> rintf (default FP rounding mode)
        kp_out[2 * bc + 0] = rintf(X / Z);
        kp_out[2 * bc + 1] = rintf(Y / Z);
    }
}

extern "C" void kernel_launch(void* const* d_in, const int* in_sizes, int n_in,
                              void* d_out, int out_size, void* d_ws, size_t ws_size,
                              hipStream_t stream) {
    const float* in = (const float*)d_in[0];
    const int BC = in_sizes[0] / HW_ELEMS;             // 32*200 = 6400
    float* map  = (float*)d_out;                       // [B,C,H,W]
    float* kp   = map + (size_t)BC * HW_ELEMS;         // [B,C,2]
    float* zeta = kp + (size_t)2 * BC;                 // [B,C]
    cm2kp_kernel<<<dim3(BC), dim3(NT), 0, stream>>>(in, map, kp, zeta);
}

// Round 4
// 674.042 us; speedup vs baseline: 1.0066x; 1.0066x over previous
//
#include <hip/hip_runtime.h>
#include <math.h>

// Problem shape (fixed by setup_inputs): B=32, C=200, H=128, W=128, fp32.
// One block per (b,c) plane; 1024 threads x 4 float4 = 4096 float4 = 16384 elems.
//
// v3 theory: timed region includes ~270us harness poison-fill (rocprof: our
// kernel < 264us, below all fillBufferAligned dispatches). Kernel portion is
// ~250us vs ~150us floor (838MB @ ~5.5TB/s). v2's phase-2 re-read spilled
// past the 4MiB per-XCD L2 (8MB/XCD resident). v3 = register-resident
// single-pass with MINIMAL retention: 4 float4/thread (16 VGPR) at 1024
// threads/block -> ~48 VGPR total, 2 blocks/CU = 32 waves/CU (full), 4x
// shorter load-drain before the barrier, zero re-read traffic (419MB in +
// 419MB out strict), non-temporal stores.
// (Round 3 was an infra failure — resubmitting identical source.)

#define HW_ELEMS 16384   // 128*128
#define WDIM 128
#define NT 1024          // threads per block (16 waves)
#define F4PT 4           // float4 per thread: 4096/1024
#define NWAVE 16

typedef float nfloat4 __attribute__((ext_vector_type(4)));

__global__ __launch_bounds__(NT) void cm2kp_kernel(
    const float* __restrict__ in,
    float* __restrict__ map_out,
    float* __restrict__ kp_out,
    float* __restrict__ zeta_out)
{
    const int bc = blockIdx.x;
    const float4* __restrict__ src = (const float4*)(in + (size_t)bc * HW_ELEMS);
    nfloat4* __restrict__ dst = (nfloat4*)(map_out + (size_t)bc * HW_ELEMS);
    const int t = threadIdx.x;
    const int wave = t >> 6;
    const int lane = t & 63;

    // ---- Phase 1: load 4 float4 into registers, per-thread min/max ----
    float4 v[F4PT];
    float vmin =  3.402823466e38f;
    float vmax = -3.402823466e38f;
    #pragma unroll
    for (int i = 0; i < F4PT; ++i) {
        v[i] = src[i * NT + t];                         // coalesced 16B/lane
        vmin = fminf(vmin, fminf(fminf(v[i].x, v[i].y), fminf(v[i].z, v[i].w)));
        vmax = fmaxf(vmax, fmaxf(fmaxf(v[i].x, v[i].y), fmaxf(v[i].z, v[i].w)));
    }
    #pragma unroll
    for (int off = 32; off > 0; off >>= 1) {
        vmin = fminf(vmin, __shfl_down(vmin, off, 64));
        vmax = fmaxf(vmax, __shfl_down(vmax, off, 64));
    }
    __shared__ float smin[NWAVE], smax[NWAVE];
    if (lane == 0) { smin[wave] = vmin; smax[wave] = vmax; }
    __syncthreads();
    float bmin = smin[0], bmax = smax[0];
    #pragma unroll
    for (int w = 1; w < NWAVE; ++w) {                   // LDS broadcast reads
        bmin = fminf(bmin, smin[w]);
        bmax = fmaxf(bmax, smax[w]);
    }
    // Reference divides by max (NOT max-min). One IEEE divide per block,
    // then multiply: <=1 ulp extra error vs per-element divide (verified,
    // absmax == 0.0 in round 2).
    const float inv = 1.0f / bmax;

    // ---- Phase 2: normalize from registers, nt-store, accumulate ----
    float zeta = 0.0f, kpx = 0.0f, kpy = 0.0f;
    #pragma unroll
    for (int i = 0; i < F4PT; ++i) {
        const int idx = i * NT + t;
        const int e = idx * 4;                          // element offset in plane
        const float x0 = (float)(e & (WDIM - 1));       // w coord (128%4==0, no wrap)
        const float y0 = (float)(e >> 7);               // h coord
        nfloat4 m;
        m.x = (v[i].x - bmin) * inv;
        m.y = (v[i].y - bmin) * inv;
        m.z = (v[i].z - bmin) * inv;
        m.w = (v[i].w - bmin) * inv;
        __builtin_nontemporal_store(m, &dst[idx]);      // stream out, no cache pollution
        const float s = m.x + m.y + m.z + m.w;
        zeta += s;
        // m.x*x0 + m.y*(x0+1) + m.z*(x0+2) + m.w*(x0+3) = s*x0 + m.y + 2m.z + 3m.w
        kpx  += s * x0 + m.y + 2.0f * m.z + 3.0f * m.w;
        kpy  += s * y0;
    }

    #pragma unroll
    for (int off = 32; off > 0; off >>= 1) {
        zeta += __shfl_down(zeta, off, 64);
        kpx  += __shfl_down(kpx,  off, 64);
        kpy  += __shfl_down(kpy,  off, 64);
    }
    __shared__ float sz[NWAVE], sx[NWAVE], sy[NWAVE];
    if (lane == 0) { sz[wave] = zeta; sx[wave] = kpx; sy[wave] = kpy; }
    __syncthreads();
    if (t == 0) {
        float Z = 0.0f, X = 0.0f, Y = 0.0f;
        #pragma unroll
        for (int w = 0; w < NWAVE; ++w) { Z += sz[w]; X += sx[w]; Y += sy[w]; }
        zeta_out[bc] = Z;
        // jnp.round = half-to-even -> rintf (default FP rounding mode)
        kp_out[2 * bc + 0] = rintf(X / Z);
        kp_out[2 * bc + 1] = rintf(Y / Z);
    }
}

extern "C" void kernel_launch(void* const* d_in, const int* in_sizes, int n_in,
                              void* d_out, int out_size, void* d_ws, size_t ws_size,
                              hipStream_t stream) {
    const float* in = (const float*)d_in[0];
    const int BC = in_sizes[0] / HW_ELEMS;             // 32*200 = 6400
    float* map  = (float*)d_out;                       // [B,C,H,W]
    float* kp   = map + (size_t)BC * HW_ELEMS;         // [B,C,2]
    float* zeta = kp + (size_t)2 * BC;                 // [B,C]
    cm2kp_kernel<<<dim3(BC), dim3(NT), 0, stream>>>(in, map, kp, zeta);
}